// Round 8
// baseline (611.763 us; speedup 1.0000x reference)
//
#include <hip/hip_runtime.h>
#include <cmath>

#define B_  4
#define DM  1024
#define LL  2048
#define HH  256

#define KBSTRIDE 2120   // bf16 elems per shifted copy

typedef short bf16x8 __attribute__((ext_vector_type(8)));
typedef float f32x4 __attribute__((ext_vector_type(4)));

__device__ __forceinline__ float gelu_exact(float x) {
    return x * 0.5f * (1.0f + erff(x * 0.70710678118654752f));
}
__device__ __forceinline__ unsigned short f2b(float f) {
    unsigned int x = __float_as_uint(f);
    unsigned int r = x + 0x7FFFu + ((x >> 16) & 1u);
    return (unsigned short)(r >> 16);
}
__device__ __forceinline__ float b2f(unsigned short u) {
    return __uint_as_float(((unsigned int)u) << 16);
}
__device__ __forceinline__ int cvt_pk_bf16(float lo, float hi) {
    int r;
    asm("v_cvt_pk_bf16_f32 %0, %1, %2" : "=v"(r) : "v"(lo), "v"(hi));
    return r;
}

// ---------------------------------------------------------------------------
// Kernel 1: build k_key (1024 x 2048, bf16) and k_v (256 x 2048, f32)
// ---------------------------------------------------------------------------
__global__ __launch_bounds__(256) void build_kernels_kernel(
        const float* __restrict__ src_key,   // (6, 1024, 64)
        const float* __restrict__ src_v,     // (6, 256, 64)
        unsigned short* __restrict__ k_key,  // (1024, 2048) bf16
        float* __restrict__ k_v) {           // (256, 2048) f32
    int bid = blockIdx.x;
    const float* src;
    int chanstride;
    bool is_key = bid < DM;
    if (is_key) {
        src = src_key + (size_t)bid * 64;
        chanstride = DM * 64;
    } else {
        src = src_v + (size_t)(bid - DM) * 64;
        chanstride = HH * 64;
    }
    int t = threadIdx.x;
    float vals[8];
    float ss = 0.0f;
#pragma unroll
    for (int r = 0; r < 8; ++r) {
        int j = r * 256 + t;
        int i, start, scale;
        if (j < 64)        { i = 0; start = 0;    scale = 1;  }
        else if (j < 128)  { i = 1; start = 64;   scale = 1;  }
        else if (j < 256)  { i = 2; start = 128;  scale = 2;  }
        else if (j < 512)  { i = 3; start = 256;  scale = 4;  }
        else if (j < 1024) { i = 4; start = 512;  scale = 8;  }
        else               { i = 5; start = 1024; scale = 16; }
        int jj = j - start;
        float pos = ((float)jj + 0.5f) / (float)scale - 0.5f;
        pos = fminf(fmaxf(pos, 0.0f), 63.0f);
        int lo = (int)pos;
        int hi = min(lo + 1, 63);
        float w = pos - (float)lo;
        const float* s = src + (size_t)i * chanstride;
        float x0 = s[lo], x1 = s[hi];
        float mult = (float)(1 << (5 - i));
        float vv = (x0 * (1.0f - w) + x1 * w) * mult;
        vals[r] = vv;
        ss += vv * vv;
    }
#pragma unroll
    for (int off = 32; off > 0; off >>= 1) ss += __shfl_down(ss, off, 64);
    __shared__ float red[4];
    __shared__ float norm_s;
    if ((t & 63) == 0) red[t >> 6] = ss;
    __syncthreads();
    if (t == 0) norm_s = sqrtf(red[0] + red[1] + red[2] + red[3]);
    __syncthreads();
    float nrm = norm_s;
    if (is_key) {
        unsigned short* dst = k_key + (size_t)bid * LL;
#pragma unroll
        for (int r = 0; r < 8; ++r) dst[r * 256 + t] = f2b(vals[r] / nrm);
    } else {
        float* dst = k_v + (size_t)(bid - DM) * LL;
#pragma unroll
        for (int r = 0; r < 8; ++r) dst[r * 256 + t] = vals[r] / nrm;
    }
}

// ---------------------------------------------------------------------------
// Kernel 2a: W f32 (1024x1024) -> bf16
// ---------------------------------------------------------------------------
__global__ __launch_bounds__(256) void wcvt_kernel(
        const float* __restrict__ src, unsigned short* __restrict__ dst) {
    int i = (blockIdx.x * 256 + threadIdx.x) * 4;
    float4 x = *(const float4*)(src + i);
    ushort4 o;
    o.x = f2b(x.x); o.y = f2b(x.y); o.z = f2b(x.z); o.w = f2b(x.w);
    *(ushort4*)(dst + i) = o;
}

// ---------------------------------------------------------------------------
// Kernel 2b: transpose+convert: src (B,1024,2048) f32 -> dst (B,2048,1024) bf16
// ---------------------------------------------------------------------------
__global__ __launch_bounds__(256) void transpose_cvt_kernel(
        const float* __restrict__ src, unsigned short* __restrict__ dst,
        int do_gelu) {
    __shared__ float tile[64][65];
    int l0 = blockIdx.x << 6;
    int h0 = blockIdx.y << 6;
    int b  = blockIdx.z;
    int t = threadIdx.x;
    int r = t >> 4, c4 = (t & 15) << 2;
    const float* s = src + ((size_t)b * DM + h0) * LL + l0;
#pragma unroll
    for (int p = 0; p < 4; ++p) {
        float4 x = *(const float4*)(s + (size_t)(p * 16 + r) * LL + c4);
        tile[p * 16 + r][c4 + 0] = x.x;
        tile[p * 16 + r][c4 + 1] = x.y;
        tile[p * 16 + r][c4 + 2] = x.z;
        tile[p * 16 + r][c4 + 3] = x.w;
    }
    __syncthreads();
    unsigned short* d = dst + ((size_t)b * LL + l0) * DM + h0;
#pragma unroll
    for (int p = 0; p < 4; ++p) {
        int lr = p * 16 + r;
        float x0 = tile[c4 + 0][lr];
        float x1 = tile[c4 + 1][lr];
        float x2 = tile[c4 + 2][lr];
        float x3 = tile[c4 + 3][lr];
        if (do_gelu) {
            x0 = gelu_exact(x0); x1 = gelu_exact(x1);
            x2 = gelu_exact(x2); x3 = gelu_exact(x3);
        }
        ushort4 o;
        o.x = f2b(x0); o.y = f2b(x1); o.z = f2b(x2); o.w = f2b(x3);
        *(ushort4*)(d + (size_t)lr * DM + c4) = o;
    }
}

// ---------------------------------------------------------------------------
// Kernel 3: MFMA GEMM.  C[b,o,l] = bias[o] + sum_h A[o,h] * Ubf[b,l,h]
// ---------------------------------------------------------------------------
__global__ __launch_bounds__(256) void gemm_mfma_kernel(
        const unsigned short* __restrict__ A,
        const unsigned short* __restrict__ Ubf,
        const float* __restrict__ bias,
        float* __restrict__ C) {
    __shared__ unsigned short As[128 * 64];
    __shared__ unsigned short Bs[128 * 64];
    int bidx = blockIdx.x;
    int b = bidx >> 4;
    int n0 = (bidx & 15) << 7;
    int m0 = blockIdx.y << 7;
    int t = threadIdx.x;
    int lane = t & 63, wave = t >> 6;
    int wr = wave >> 1, wc = wave & 1;

    const unsigned short* Ub = Ubf + (size_t)b * LL * DM;

    f32x4 acc[4][4];
#pragma unroll
    for (int i = 0; i < 4; ++i)
#pragma unroll
        for (int j = 0; j < 4; ++j) {
            f32x4 z = {0.0f, 0.0f, 0.0f, 0.0f};
            acc[i][j] = z;
        }

    int srow = t >> 3;
    int scol = (t & 7) << 3;
    int lrow = lane & 15;
    int lk = (lane >> 4) << 3;

    for (int k0 = 0; k0 < DM; k0 += 64) {
        __syncthreads();
#pragma unroll
        for (int p = 0; p < 4; ++p) {
            int row = p * 32 + srow;
            uint4 av = *(const uint4*)(A  + (size_t)(m0 + row) * DM + k0 + scol);
            uint4 bv = *(const uint4*)(Ub + (size_t)(n0 + row) * DM + k0 + scol);
            *(uint4*)&As[row * 64 + scol] = av;
            *(uint4*)&Bs[row * 64 + scol] = bv;
        }
        __syncthreads();
#pragma unroll
        for (int kk = 0; kk < 64; kk += 32) {
            bf16x8 af[4], bfr[4];
#pragma unroll
            for (int mi = 0; mi < 4; ++mi)
                af[mi] = *(const bf16x8*)&As[(wr * 64 + mi * 16 + lrow) * 64 + kk + lk];
#pragma unroll
            for (int ni = 0; ni < 4; ++ni)
                bfr[ni] = *(const bf16x8*)&Bs[(wc * 64 + ni * 16 + lrow) * 64 + kk + lk];
#pragma unroll
            for (int mi = 0; mi < 4; ++mi)
#pragma unroll
                for (int ni = 0; ni < 4; ++ni)
                    acc[mi][ni] = __builtin_amdgcn_mfma_f32_16x16x32_bf16(
                        af[mi], bfr[ni], acc[mi][ni], 0, 0, 0);
        }
    }
    int rg = (lane >> 4) << 2;
    int cn = lane & 15;
#pragma unroll
    for (int mi = 0; mi < 4; ++mi) {
#pragma unroll
        for (int r = 0; r < 4; ++r) {
            int o = m0 + wr * 64 + mi * 16 + rg + r;
            float bo = bias[o];
            float* crow = C + ((size_t)b * DM + o) * LL + n0 + wc * 64;
#pragma unroll
            for (int ni = 0; ni < 4; ++ni)
                crow[ni * 16 + cn] = acc[mi][ni][r] + bo;
        }
    }
}

// ---------------------------------------------------------------------------
// Kernel 4: key-side causal conv + skip via Toeplitz MFMA, B-ring registers.
// B-frag depends on (s,m) only via j = s+4m. Process s in 4 residue streams
// (s = r+4si); 16-slot ring Bv[(si+m)&15]; 1 ds_read_b128 per si.
// ---------------------------------------------------------------------------
__global__ __launch_bounds__(512, 2) void key_conv_mfma_kernel(
        const float* __restrict__ kk_raw,        // (B, 1024, 2048)
        const unsigned short* __restrict__ k_key,// (1024, 2048) bf16
        const float* __restrict__ D_key,         // (1024)
        float* __restrict__ knew) {              // (B, 1024, 2048)
    __shared__ unsigned short Kb[8 * KBSTRIDE];  // ~33.1 KB
    int c = blockIdx.x;
    int tid = threadIdx.x;

    const unsigned short* kp = k_key + (size_t)c * LL;
#pragma unroll
    for (int r = 0; r < 8; ++r) {
        for (int x = tid; x < 2096; x += 512) {
            int src = x + r - 48;   // Kpad[j] = K[j-48], zero-padded
            Kb[r * KBSTRIDE + x] =
                (src >= 0 && src < LL) ? kp[src] : (unsigned short)0;
        }
    }
    __syncthreads();

    int w = tid >> 6, lane = tid & 63;
    int n = lane & 15, kgrp = lane >> 4;
    float zmask = (n < 4) ? 1.0f : 0.0f;
    int brow = (n < 4) ? n : 0;
    const float* pk = kk_raw + ((size_t)brow * DM + c) * LL;

    f32x4 acc[16];
#pragma unroll
    for (int m = 0; m < 16; ++m) {
        f32x4 z = {0.0f, 0.0f, 0.0f, 0.0f};
        acc[m] = z;
    }

    int idx0 = 16 * w + n + 8 * kgrp - 1999;
    int rsh = (n + 1) & 7;                       // == idx0 mod 8
    const unsigned short* kbp = &Kb[rsh * KBSTRIDE];
    int aoff0 = idx0 - rsh;                      // 8-elem aligned base

    bf16x8 Bv[16];
    for (int r = 0; r < 4; ++r) {
        int off0 = aoff0 + (r << 5);
        // prologue: fragments i = 0..14 -> slots 0..14
#pragma unroll
        for (int i = 0; i < 15; ++i) {
            int off = off0 + (i << 7);
            off = off < 0 ? 0 : off;
            Bv[i] = *(const bf16x8*)(kbp + off);
        }
#pragma unroll
        for (int si = 0; si < 16; ++si) {
            {   // load fragment i = si+15 into slot (si+15)&15
                int off = off0 + ((si + 15) << 7);
                off = off < 0 ? 0 : off;
                Bv[(si + 15) & 15] = *(const bf16x8*)(kbp + off);
            }
            int s = r + (si << 2);
            int msv = (2128 - (s << 5) - 16 * w) >> 7;
            msv = msv < 0 ? 0 : msv;
            int ms = __builtin_amdgcn_readfirstlane(msv);
            if (ms >= 16) continue;

            int tb = 2040 - (s << 5) - 8 * kgrp;
            float4 ka = *(const float4*)(pk + tb);
            float4 kb = *(const float4*)(pk + tb + 4);
            float p0 = kb.w * zmask;
            float p1 = kb.z * zmask;
            float p2 = kb.y * zmask;
            float p3 = kb.x * zmask;
            float p4 = ka.w * zmask;
            float p5 = ka.z * zmask;
            float p6 = ka.y * zmask;
            float p7 = ka.x * zmask;
            int4 ai;
            ai.x = cvt_pk_bf16(p0, p1);
            ai.y = cvt_pk_bf16(p2, p3);
            ai.z = cvt_pk_bf16(p4, p5);
            ai.w = cvt_pk_bf16(p6, p7);
            bf16x8 afrag = __builtin_bit_cast(bf16x8, ai);

#pragma unroll
            for (int m = 0; m < 16; ++m) {
                if (m >= ms) {
                    acc[m] = __builtin_amdgcn_mfma_f32_16x16x32_bf16(
                        afrag, Bv[(si + m) & 15], acc[m], 0, 0, 0);
                }
            }
        }
    }

    // epilogue: rows 0-3 live in g==0 lanes, reg index = b. D_key skip fused.
    int g = lane >> 4;
    if (g == 0) {
        float dk = D_key[c];
#pragma unroll
        for (int m = 0; m < 16; ++m) {
            int lm = 16 * w + 128 * m + n;
#pragma unroll
            for (int b = 0; b < 4; ++b) {
                size_t off = ((size_t)b * DM + c) * LL + lm;
                knew[off] = acc[m][b] + kk_raw[off] * dk;
            }
        }
    }
}

// ---------------------------------------------------------------------------
// Kernel 5: value-side gated conv via Toeplitz MFMA, B-ring registers.
// ---------------------------------------------------------------------------
__global__ __launch_bounds__(512, 2) void value_conv_mfma_kernel(
        const float* __restrict__ knew,  // (B, 1024, 2048)
        const float* __restrict__ v,     // (B, 1024, 2048)
        const float* __restrict__ q,     // (B, 1024, 2048)
        const float* __restrict__ k_v,   // (256, 2048) f32
        const float* __restrict__ Dv,    // (256)
        float* __restrict__ y_g) {       // (B, 1024, 2048), channel = d2*256+hh
    __shared__ unsigned short Kb[8 * KBSTRIDE];  // ~33.1 KB
    int bid = blockIdx.x;
    int hh = bid & 255, b = bid >> 8;
    int tid = threadIdx.x;

    const float* kvp = k_v + (size_t)hh * LL;
#pragma unroll
    for (int r = 0; r < 8; ++r) {
        for (int x = tid; x < 2096; x += 512) {
            int src = x + r - 48;
            Kb[r * KBSTRIDE + x] =
                (src >= 0 && src < LL) ? f2b(kvp[src]) : (unsigned short)0;
        }
    }
    __syncthreads();

    int w = tid >> 6, lane = tid & 63;
    int n = lane & 15, kgrp = lane >> 4;
    int d1a = n >> 2, d2a = n & 3;

    const float* pk = knew + ((size_t)b * DM + hh * 4 + d1a) * LL;
    const float* pv = v    + ((size_t)b * DM + hh * 4 + d2a) * LL;

    f32x4 acc[16];
#pragma unroll
    for (int m = 0; m < 16; ++m) {
        f32x4 z = {0.0f, 0.0f, 0.0f, 0.0f};
        acc[m] = z;
    }

    int idx0 = 16 * w + n + 8 * kgrp - 1999;
    int rsh = (n + 1) & 7;
    const unsigned short* kbp = &Kb[rsh * KBSTRIDE];
    int aoff0 = idx0 - rsh;

    bf16x8 Bv[16];
    for (int r = 0; r < 4; ++r) {
        int off0 = aoff0 + (r << 5);
#pragma unroll
        for (int i = 0; i < 15; ++i) {
            int off = off0 + (i << 7);
            off = off < 0 ? 0 : off;
            Bv[i] = *(const bf16x8*)(kbp + off);
        }
#pragma unroll
        for (int si = 0; si < 16; ++si) {
            {
                int off = off0 + ((si + 15) << 7);
                off = off < 0 ? 0 : off;
                Bv[(si + 15) & 15] = *(const bf16x8*)(kbp + off);
            }
            int s = r + (si << 2);
            int msv = (2128 - (s << 5) - 16 * w) >> 7;
            msv = msv < 0 ? 0 : msv;
            int ms = __builtin_amdgcn_readfirstlane(msv);
            if (ms >= 16) continue;

            int tb = 2040 - (s << 5) - 8 * kgrp;
            float4 ka = *(const float4*)(pk + tb);
            float4 kb = *(const float4*)(pk + tb + 4);
            float4 va = *(const float4*)(pv + tb);
            float4 vb = *(const float4*)(pv + tb + 4);
            float p0 = kb.w * vb.w;
            float p1 = kb.z * vb.z;
            float p2 = kb.y * vb.y;
            float p3 = kb.x * vb.x;
            float p4 = ka.w * va.w;
            float p5 = ka.z * va.z;
            float p6 = ka.y * va.y;
            float p7 = ka.x * va.x;
            int4 ai;
            ai.x = cvt_pk_bf16(p0, p1);
            ai.y = cvt_pk_bf16(p2, p3);
            ai.z = cvt_pk_bf16(p4, p5);
            ai.w = cvt_pk_bf16(p6, p7);
            bf16x8 afrag = __builtin_bit_cast(bf16x8, ai);

#pragma unroll
            for (int m = 0; m < 16; ++m) {
                if (m >= ms) {
                    acc[m] = __builtin_amdgcn_mfma_f32_16x16x32_bf16(
                        afrag, Bv[(si + m) & 15], acc[m], 0, 0, 0);
                }
            }
        }
    }

    int g = lane >> 4;
    float Dh = Dv[hh];
    const float* qrow = q    + ((size_t)b * DM + hh * 4 + g) * LL;
    const float* krow = knew + ((size_t)b * DM + hh * 4 + g) * LL;
    const float* vb0  = v    + ((size_t)b * DM + hh * 4) * LL;
#pragma unroll
    for (int m = 0; m < 16; ++m) {
        int lm = 16 * w + 128 * m + n;
        float qv = qrow[lm];
        float kl = krow[lm];
        float vl0 = vb0[lm];
        float vl1 = vb0[(size_t)1 * LL + lm];
        float vl2 = vb0[(size_t)2 * LL + lm];
        float vl3 = vb0[(size_t)3 * LL + lm];
        float part0 = qv * (acc[m][0] + kl * vl0 * Dh);
        float part1 = qv * (acc[m][1] + kl * vl1 * Dh);
        float part2 = qv * (acc[m][2] + kl * vl2 * Dh);
        float part3 = qv * (acc[m][3] + kl * vl3 * Dh);
        part0 += __shfl_xor(part0, 16, 64); part0 += __shfl_xor(part0, 32, 64);
        part1 += __shfl_xor(part1, 16, 64); part1 += __shfl_xor(part1, 32, 64);
        part2 += __shfl_xor(part2, 16, 64); part2 += __shfl_xor(part2, 32, 64);
        part3 += __shfl_xor(part3, 16, 64); part3 += __shfl_xor(part3, 32, 64);
        float outv = (g == 0) ? part0 : (g == 1) ? part1 : (g == 2) ? part2 : part3;
        y_g[((size_t)b * DM + (size_t)g * 256 + hh) * LL + lm] = outv;
    }
}

// ---------------------------------------------------------------------------
extern "C" void kernel_launch(void* const* d_in, const int* in_sizes, int n_in,
                              void* d_out, int out_size, void* d_ws, size_t ws_size,
                              hipStream_t stream) {
    const float* u       = (const float*)d_in[0];
    const float* q_w     = (const float*)d_in[1];
    const float* q_b     = (const float*)d_in[2];
    const float* k_w     = (const float*)d_in[3];
    const float* k_b     = (const float*)d_in[4];
    const float* v_w     = (const float*)d_in[5];
    const float* v_b     = (const float*)d_in[6];
    const float* kern_k  = (const float*)d_in[7];
    const float* kern_v  = (const float*)d_in[8];
    const float* D_key   = (const float*)d_in[9];
    const float* D_v     = (const float*)d_in[10];
    const float* pw_w    = (const float*)d_in[11];
    const float* pw_b    = (const float*)d_in[12];
    float* out = (float*)d_out;

    const size_t BDL = (size_t)B_ * DM * LL;
    char* p = (char*)d_ws;
    float*          w_kv   = (float*)p;          p += (size_t)HH * LL * 4;
    unsigned short* w_kkey = (unsigned short*)p; p += (size_t)DM * LL * 2;
    unsigned short* w_wbuf = (unsigned short*)p; p += (size_t)DM * DM * 2;
    float*          w_R0   = (float*)p;          p += BDL * 4;
    float*          w_q    = (float*)p;          p += BDL * 4;
    float*          w_ky   = (float*)p;          p += BDL * 4;
    float*          w_v    = (float*)p;          p += BDL * 4;
    unsigned short* w_uT   = (unsigned short*)w_R0;
    unsigned short* w_ygT  = (unsigned short*)w_R0;
    float*          w_knew = w_R0;
    float*          w_yg   = w_ky;

    // 1. build kernels
    build_kernels_kernel<<<DM + HH, 256, 0, stream>>>(kern_k, kern_v, w_kkey, w_kv);

    // 2. u -> u_T bf16
    dim3 tgrid(LL / 64, DM / 64, B_);
    transpose_cvt_kernel<<<tgrid, 256, 0, stream>>>(u, w_uT, 0);

    // 3. projections (bf16 MFMA)
    dim3 ggrid(B_ * (LL / 128), DM / 128);
    wcvt_kernel<<<DM * DM / 1024, 256, 0, stream>>>(q_w, w_wbuf);
    gemm_mfma_kernel<<<ggrid, 256, 0, stream>>>(w_wbuf, w_uT, q_b, w_q);
    wcvt_kernel<<<DM * DM / 1024, 256, 0, stream>>>(k_w, w_wbuf);
    gemm_mfma_kernel<<<ggrid, 256, 0, stream>>>(w_wbuf, w_uT, k_b, w_ky);
    wcvt_kernel<<<DM * DM / 1024, 256, 0, stream>>>(v_w, w_wbuf);
    gemm_mfma_kernel<<<ggrid, 256, 0, stream>>>(w_wbuf, w_uT, v_b, w_v);

    // 4. key conv + skip via Toeplitz MFMA (u_T dead; knew takes over R0)
    key_conv_mfma_kernel<<<DM, 512, 0, stream>>>(w_ky, w_kkey, D_key, w_knew);

    // 5. value conv + gating via Toeplitz MFMA (y_g overwrites kraw)
    value_conv_mfma_kernel<<<B_ * HH, 512, 0, stream>>>(
        w_knew, w_v, w_q, w_kv, D_v, w_yg);

    // 6. y_g -> gelu -> yg_T bf16
    transpose_cvt_kernel<<<tgrid, 256, 0, stream>>>(w_yg, w_ygT, 1);

    // 7. pointwise projection
    wcvt_kernel<<<DM * DM / 1024, 256, 0, stream>>>(pw_w, w_wbuf);
    gemm_mfma_kernel<<<ggrid, 256, 0, stream>>>(w_wbuf, w_ygT, pw_b, out);
}